// Round 25
// baseline (653.234 us; speedup 1.0000x reference)
//
#include <hip/hip_runtime.h>
#include <hip/hip_bf16.h>

// ABLATION ROUND v2: REP-scaled variants so ablation dispatches clear the
// ~58us top-5 filter (fillBuffer poison kernels). Dynamic rep loop
// (unroll 1, memory clobber per rep) keeps code size = 1x K-loop.
//   <3,10>, <3,5>: prologue + MFMA-only loop  (2 REP points -> linear fit)
//   <2,5>: + in-loop ds_read fragment reads (no staging)
//   <1,5>: + staging & counted waits (full K-loop), no epilogue
//   <0,1>: full kernel, launched LAST (sole writer of out)
// Base: R20 int8 implicit GEMM, wave-private 2-slot B ring, transposed-D.

typedef __attribute__((ext_vector_type(4))) int   i32x4;
typedef __attribute__((ext_vector_type(4))) float f32x4;

#define WTI8_BYTES (18 * 16384)
#define XPI8_BYTES (32 * 58 * 8192)

__device__ __forceinline__ void gload_lds16(const void* g, void* l) {
    __builtin_amdgcn_global_load_lds(
        (const __attribute__((address_space(1))) void*)g,
        (__attribute__((address_space(3))) void*)l, 16, 0, 0);
}

// ---- weight prep: w[cout][cin][3][3] - 128 -> per-(s,wn) 4KB panels ----
__global__ void wprep_kernel(const float* __restrict__ w, char* __restrict__ wt) {
    int cidx = blockIdx.x * 256 + threadIdx.x;
    int byte0 = cidx * 16;
    int s    = byte0 >> 14;
    int wn   = (byte0 >> 12) & 3;
    int e4   = byte0 & 4095;
    int nn   = e4 >> 6;
    int koff = e4 & 63;
    int kl   = koff ^ ((nn & 3) << 4);
    int n = wn * 64 + nn;
    int r = s >> 1, ch = s & 1;
    union { char c[16]; i32x4 v; } u;
#pragma unroll
    for (int j = 0; j < 16; ++j) {
        int cin = ch * 64 + kl + j;
        u.c[j] = (char)((int)w[(size_t)n * 1152 + cin * 9 + r] - 128);
    }
    *(i32x4*)(wt + byte0) = u.v;
}

// ---- x prep: coalesced NCHW read -> swizzled padded NHWC int8 + colsum ----
__global__ void xprep_kernel(const float* __restrict__ x, const float* __restrict__ xzp,
                             char* __restrict__ xpi8, int* __restrict__ colsum) {
    int bhh = blockIdx.x;
    int b = bhh / 58, hh = bhh % 58;
    int tid = threadIdx.x;
    char* blob = xpi8 + (size_t)bhh * 8192;
    int w  = tid & 63;
    int cq = tid >> 6;
    __shared__ int ps[4][64];
    if (hh == 0 || hh == 57) {
        i32x4 z = {0, 0, 0, 0};
        *(i32x4*)(blob + tid * 32)      = z;
        *(i32x4*)(blob + tid * 32 + 16) = z;
        if (cq == 0) colsum[bhh * 64 + w] = 0;
        return;
    }
    const int ZX = (int)rintf(*xzp);
    bool valid = (w >= 1 && w <= 56);
    const float* xb = x + (size_t)b * 128 * 3136 + (size_t)(hh - 1) * 56 +
                      (valid ? (w - 1) : 0);
    int csum = 0;
#pragma unroll
    for (int u = 0; u < 2; ++u) {
        union { char c[16]; i32x4 v; } uu;
#pragma unroll
        for (int j = 0; j < 16; ++j) {
            int c = cq * 32 + u * 16 + j;
            int val = valid ? ((int)xb[(size_t)c * 3136] - ZX) : 0;
            uu.c[j] = (char)val;
            csum += val;
        }
        *(i32x4*)(blob + w * 128 + ((cq * 32 + u * 16) ^ ((w & 7) << 4))) = uu.v;
    }
    ps[cq][w] = csum;
    __syncthreads();
    if (cq == 0)
        colsum[bhh * 64 + w] = ps[0][w] + ps[1][w] + ps[2][w] + ps[3][w];
}

// ---- conv variants ----
template <int MODE, int REP>
__global__ __launch_bounds__(256, 2)
void conv_kernel(const char* __restrict__ wt,
                 const char* __restrict__ xpi8,
                 const int* __restrict__ colsum,
                 const float* __restrict__ bias,
                 const float* __restrict__ Mp,
                 const float* __restrict__ wzp,
                 const float* __restrict__ yzp,
                 float* __restrict__ out) {
    __shared__ __align__(1024) char As[32768];
    __shared__ __align__(1024) char Bp[32768];
    __shared__ int s2row[2][64];

    const int tid = threadIdx.x;
    const int lane = tid & 63;
    const int wn = tid >> 6;
    const int l15 = lane & 15, lg = lane >> 4;
    const int bx = blockIdx.x;
    const int b = bx / 28;
    const int h0 = (bx % 28) * 2;

    char* bpriv = Bp + wn * 8192;
    const char* bwsrc = wt + wn * 4096 + lane * 16;
    const int bfoff = (lg * 16) ^ ((l15 & 3) << 4);

    const char* agbase = xpi8 + (size_t)(b * 58 + h0) * 8192;
#pragma unroll
    for (int i = 0; i < 8; ++i)
        gload_lds16(agbase + i * 4096 + tid * 16, As + i * 4096 + tid * 16);
#pragma unroll
    for (int st = 0; st < 2; ++st)
#pragma unroll
        for (int i = 0; i < 4; ++i)
            gload_lds16(bwsrc + (size_t)st * 16384 + i * 1024,
                        bpriv + st * 4096 + i * 1024 + lane * 16);
    if (tid < 128) {
        int row = tid >> 6, m = tid & 63;
        int s = 0;
        if (m < 56) {
#pragma unroll
            for (int kh = 0; kh < 3; ++kh)
#pragma unroll
                for (int kw = 0; kw < 3; ++kw)
                    s += colsum[(b * 58 + h0 + row + kh) * 64 + m + kw];
        }
        s2row[row][m] = s;
    }

    i32x4 acc[4][8];
#pragma unroll
    for (int i = 0; i < 4; ++i)
#pragma unroll
        for (int j = 0; j < 8; ++j)
            acc[i][j] = (i32x4){0, 0, 0, 0};

    __syncthreads();

    if constexpr (MODE == 3) {
        i32x4 bfr[4], afr[8];
#pragma unroll
        for (int fn = 0; fn < 4; ++fn)
            bfr[fn] = *(const i32x4*)(bpriv + (fn * 16 + l15) * 64 + bfoff);
#pragma unroll
        for (int fm = 0; fm < 8; ++fm) {
            int wv = (fm & 3) * 16 + l15;
            int ab = (fm >> 2) * 8192 + wv * 128 +
                     ((lg * 16) ^ ((wv & 7) << 4));
            afr[fm] = *(const i32x4*)(As + ab);
        }
#pragma unroll 1
        for (int rep = 0; rep < REP; ++rep) {
            asm volatile("" ::: "memory");
#pragma unroll
            for (int s = 0; s < 18; ++s)
#pragma unroll
                for (int fn = 0; fn < 4; ++fn)
#pragma unroll
                    for (int fm = 0; fm < 8; ++fm)
                        acc[fn][fm] = __builtin_amdgcn_mfma_i32_16x16x64_i8(
                            bfr[fn], afr[fm], acc[fn][fm], 0, 0, 0);
        }
    } else {
#pragma unroll 1
        for (int rep = 0; rep < REP; ++rep) {
            asm volatile("" ::: "memory");
#pragma unroll
            for (int s = 0; s < 18; ++s) {
                const int kh = (s >> 1) / 3, kw = (s >> 1) % 3, ch = s & 1;
                const char* bslot = bpriv + (s & 1) * 4096;
                i32x4 bfr[4];
#pragma unroll
                for (int fn = 0; fn < 4; ++fn)
                    bfr[fn] = *(const i32x4*)(bslot + (fn * 16 + l15) * 64 + bfoff);
                i32x4 afr[8];
#pragma unroll
                for (int fm = 0; fm < 8; ++fm) {
                    int wv = (fm & 3) * 16 + l15 + kw;
                    int wc = wv > 63 ? 63 : wv;
                    int ab = ((fm >> 2) + kh) * 8192 + wc * 128 +
                             ((ch * 64 + lg * 16) ^ ((wc & 7) << 4));
                    afr[fm] = *(const i32x4*)(As + ab);
                }
                if constexpr (MODE <= 1) {
                    if (s < 16) {
                        asm volatile("s_waitcnt lgkmcnt(0)" ::: "memory");
#pragma unroll
                        for (int i = 0; i < 4; ++i)
                            gload_lds16(bwsrc + (size_t)(s + 2) * 16384 + i * 1024,
                                        bpriv + (s & 1) * 4096 + i * 1024 + lane * 16);
                        asm volatile("s_waitcnt vmcnt(4)" ::: "memory");
                    } else if (s == 16) {
                        asm volatile("s_waitcnt vmcnt(0)" ::: "memory");
                    }
                }
#pragma unroll
                for (int fn = 0; fn < 4; ++fn)
#pragma unroll
                    for (int fm = 0; fm < 8; ++fm)
                        acc[fn][fm] = __builtin_amdgcn_mfma_i32_16x16x64_i8(
                            bfr[fn], afr[fm], acc[fn][fm], 0, 0, 0);
            }
        }
    }

    if constexpr (MODE == 0) {
        const float Mv  = *Mp;
        const float yzv = *yzp;
        const float CWf = 128.0f - *wzp;
#pragma unroll
        for (int fn = 0; fn < 4; ++fn) {
#pragma unroll
            for (int reg = 0; reg < 4; ++reg) {
                const int cout = wn * 64 + fn * 16 + lg * 4 + reg;
                const float bv = bias[cout];
#pragma unroll
                for (int fm = 0; fm < 8; ++fm) {
                    const int row = fm >> 2;
                    const int m = (fm & 3) * 16 + l15;
                    if (m < 56) {
                        const size_t rowb =
                            ((size_t)(b * 256 + cout) * 56 + h0 + row) * 56;
                        float af = (float)acc[fn][fm][reg] +
                                   CWf * (float)s2row[row][m];
                        float v = (af + bv) * Mv + yzv;
                        v = fmaxf(v, yzv);
                        out[rowb + m] = rintf(v);
                    }
                }
            }
        }
    } else {
#pragma unroll
        for (int fn = 0; fn < 4; ++fn)
#pragma unroll
            for (int fm = 0; fm < 8; ++fm)
#pragma unroll
                for (int reg = 0; reg < 4; ++reg)
                    asm volatile("" :: "v"(acc[fn][fm][reg]));
    }
}

extern "C" void kernel_launch(void* const* d_in, const int* in_sizes, int n_in,
                              void* d_out, int out_size, void* d_ws, size_t ws_size,
                              hipStream_t stream) {
    const float* x    = (const float*)d_in[0];
    const float* w    = (const float*)d_in[1];
    const float* bias = (const float*)d_in[2];
    const float* Mp   = (const float*)d_in[3];
    const float* xzp  = (const float*)d_in[4];
    const float* wzp  = (const float*)d_in[5];
    const float* yzp  = (const float*)d_in[6];
    float* out = (float*)d_out;

    char* wt     = (char*)d_ws;
    char* xpi8   = wt + WTI8_BYTES;
    int*  colsum = (int*)(xpi8 + XPI8_BYTES);

    wprep_kernel<<<72, 256, 0, stream>>>(w, wt);
    xprep_kernel<<<32 * 58, 256, 0, stream>>>(x, xzp, xpi8, colsum);
    // REP-scaled ablation dispatches (no output writes), then the real kernel
    conv_kernel<3, 10><<<32 * 28, 256, 0, stream>>>(wt, xpi8, colsum, bias, Mp, wzp, yzp, out);
    conv_kernel<3, 5><<<32 * 28, 256, 0, stream>>>(wt, xpi8, colsum, bias, Mp, wzp, yzp, out);
    conv_kernel<2, 5><<<32 * 28, 256, 0, stream>>>(wt, xpi8, colsum, bias, Mp, wzp, yzp, out);
    conv_kernel<1, 5><<<32 * 28, 256, 0, stream>>>(wt, xpi8, colsum, bias, Mp, wzp, yzp, out);
    conv_kernel<0, 1><<<32 * 28, 256, 0, stream>>>(wt, xpi8, colsum, bias, Mp, wzp, yzp, out);
}

// Round 26
// 75.201 us; speedup vs baseline: 8.6865x; 8.6865x over previous
//
#include <hip/hip_runtime.h>
#include <hip/hip_bf16.h>

// Quantized 3x3 conv via int8 implicit GEMM — R20 K-loop (proven) +
// LDS-repack epilogue with float4 stores (R24/R25 ablation: epilogue
// marginal ~24us vs 14.5us HBM floor was the dominant non-MFMA term;
// MFMA-only loop measured 20us at MfmaUtil 78%).
// B=32, Cin=128, Cout=256, H=W=56, pad=1. M=(b,h,w64), N=256, K=9x128.
//
// (x-xz)(w-wz) = xi*wi + (128-wz)*xi,  xi=x-128 (int8), wi=w-128 (int8);
// acc = i8gemm + (128-wz)*S,  S = window-sum of xi (pads contribute 0).
//
// xpi8 blob per (b,hh), 8KB: byte(w,c) = w*128 + (c ^ ((w&7)<<4)).
// wt layout: per (s=r*2+ch, wn) a 4KB panel of 64 rows x 64B:
//   byte(nn, kl) = nn*64 + (kl ^ ((nn&3)<<4)),  n = wn*64+nn, cin = ch*64+kl.
// Involution swizzles; staged linearly via global_load_lds, read with the
// same XOR (rule #21).
//
// conv: 256 thr / 4 waves, block 128m(2 rows) x 256n; per-wave 128m x 64n
// transposed-D; wave-private 2-slot B ring, counted per-wave vmcnt, no
// in-loop barriers. Epilogue: 2 row-passes through a 256x66-float LDS
// buffer (reuses As/Bp; stride 66 -> conflict-free writes), then float4
// lane-contiguous stores (16B/lane, 4x fewer store instrs).

typedef __attribute__((ext_vector_type(4))) int   i32x4;
typedef __attribute__((ext_vector_type(4))) float f32x4;

#define WTI8_BYTES (18 * 16384)            // 294,912
#define XPI8_BYTES (32 * 58 * 8192)        // 15,204,352

__device__ __forceinline__ void gload_lds16(const void* g, void* l) {
    __builtin_amdgcn_global_load_lds(
        (const __attribute__((address_space(1))) void*)g,
        (__attribute__((address_space(3))) void*)l, 16, 0, 0);
}

// ---- fused prep: blocks <1856 do x-repack+colsum; rest do weight prep ----
__global__ void prep_kernel(const float* __restrict__ x, const float* __restrict__ xzp,
                            const float* __restrict__ w,
                            char* __restrict__ xpi8, int* __restrict__ colsum,
                            char* __restrict__ wt) {
    int tid = threadIdx.x;
    if (blockIdx.x >= 32 * 58) {
        // ---- weight prep: w[cout][cin][3][3] - 128 -> per-(s,wn) panels ----
        int cidx = (blockIdx.x - 32 * 58) * 256 + tid;   // < 18432
        int byte0 = cidx * 16;
        int s    = byte0 >> 14;
        int wn   = (byte0 >> 12) & 3;
        int e4   = byte0 & 4095;
        int nn   = e4 >> 6;
        int koff = e4 & 63;
        int kl   = koff ^ ((nn & 3) << 4);
        int n = wn * 64 + nn;
        int r = s >> 1, ch = s & 1;
        union { char c[16]; i32x4 v; } u;
#pragma unroll
        for (int j = 0; j < 16; ++j) {
            int cin = ch * 64 + kl + j;
            u.c[j] = (char)((int)w[(size_t)n * 1152 + cin * 9 + r] - 128);
        }
        *(i32x4*)(wt + byte0) = u.v;
        return;
    }
    // ---- x prep ----
    int bhh = blockIdx.x;
    int b = bhh / 58, hh = bhh % 58;
    char* blob = xpi8 + (size_t)bhh * 8192;
    int wcol = tid & 63;
    int cq = tid >> 6;
    __shared__ int ps[4][64];
    if (hh == 0 || hh == 57) {
        i32x4 z = {0, 0, 0, 0};
        *(i32x4*)(blob + tid * 32)      = z;
        *(i32x4*)(blob + tid * 32 + 16) = z;
        if (cq == 0) colsum[bhh * 64 + wcol] = 0;
        return;
    }
    const int ZX = (int)rintf(*xzp);
    bool valid = (wcol >= 1 && wcol <= 56);
    const float* xb = x + (size_t)b * 128 * 3136 + (size_t)(hh - 1) * 56 +
                      (valid ? (wcol - 1) : 0);
    int csum = 0;
#pragma unroll
    for (int u = 0; u < 2; ++u) {
        union { char c[16]; i32x4 v; } uu;
#pragma unroll
        for (int j = 0; j < 16; ++j) {
            int c = cq * 32 + u * 16 + j;
            int val = valid ? ((int)xb[(size_t)c * 3136] - ZX) : 0;
            uu.c[j] = (char)val;
            csum += val;
        }
        *(i32x4*)(blob + wcol * 128 + ((cq * 32 + u * 16) ^ ((wcol & 7) << 4))) = uu.v;
    }
    ps[cq][wcol] = csum;
    __syncthreads();
    if (cq == 0)
        colsum[bhh * 64 + wcol] = ps[0][wcol] + ps[1][wcol] + ps[2][wcol] + ps[3][wcol];
}

// ---- main conv ----
__global__ __launch_bounds__(256, 2)
void conv_kernel(const char* __restrict__ wt,
                 const char* __restrict__ xpi8,
                 const int* __restrict__ colsum,
                 const float* __restrict__ bias,
                 const float* __restrict__ Mp,
                 const float* __restrict__ wzp,
                 const float* __restrict__ yzp,
                 float* __restrict__ out) {
    __shared__ __align__(1024) char smem[69632];   // K-loop: As 32K + Bp 32K;
    __shared__ int s2row[2][64];                   // epilogue: 256x66 f32 buf
    char* As = smem;
    char* Bp = smem + 32768;
    float* fbuf = (float*)smem;

    const int tid = threadIdx.x;
    const int lane = tid & 63;
    const int wn = tid >> 6;
    const int l15 = lane & 15, lg = lane >> 4;
    const int bx = blockIdx.x;
    const int b = bx / 28;
    const int h0 = (bx % 28) * 2;

    char* bpriv = Bp + wn * 8192;
    const char* bwsrc = wt + wn * 4096 + lane * 16;
    const int bfoff = (lg * 16) ^ ((l15 & 3) << 4);

    // ---- prologue: A (32KB); B stages 0,1 -> slots 0,1; S2 rows ----
    const char* agbase = xpi8 + (size_t)(b * 58 + h0) * 8192;
#pragma unroll
    for (int i = 0; i < 8; ++i)
        gload_lds16(agbase + i * 4096 + tid * 16, As + i * 4096 + tid * 16);
#pragma unroll
    for (int st = 0; st < 2; ++st)
#pragma unroll
        for (int i = 0; i < 4; ++i)
            gload_lds16(bwsrc + (size_t)st * 16384 + i * 1024,
                        bpriv + st * 4096 + i * 1024 + lane * 16);
    if (tid < 128) {
        int row = tid >> 6, m = tid & 63;
        int s = 0;
        if (m < 56) {
#pragma unroll
            for (int kh = 0; kh < 3; ++kh)
#pragma unroll
                for (int kw = 0; kw < 3; ++kw)
                    s += colsum[(b * 58 + h0 + row + kh) * 64 + m + kw];
        }
        s2row[row][m] = s;
    }

    i32x4 acc[4][8];
#pragma unroll
    for (int i = 0; i < 4; ++i)
#pragma unroll
        for (int j = 0; j < 8; ++j)
            acc[i][j] = (i32x4){0, 0, 0, 0};

    __syncthreads();                               // A + B0/B1 + s2row ready

#pragma unroll
    for (int s = 0; s < 18; ++s) {                 // 9 taps x 2 cin-halves
        const int kh = (s >> 1) / 3, kw = (s >> 1) % 3, ch = s & 1;
        const char* bslot = bpriv + (s & 1) * 4096;
        i32x4 bfr[4];
#pragma unroll
        for (int fn = 0; fn < 4; ++fn)
            bfr[fn] = *(const i32x4*)(bslot + (fn * 16 + l15) * 64 + bfoff);
        i32x4 afr[8];
#pragma unroll
        for (int fm = 0; fm < 8; ++fm) {
            int wv = (fm & 3) * 16 + l15 + kw;
            int wc = wv > 63 ? 63 : wv;            // clamped lanes: dead outputs
            int ab = ((fm >> 2) + kh) * 8192 + wc * 128 +
                     ((ch * 64 + lg * 16) ^ ((wc & 7) << 4));
            afr[fm] = *(const i32x4*)(As + ab);
        }
        if (s < 16) {
            asm volatile("s_waitcnt lgkmcnt(0)" ::: "memory");
#pragma unroll
            for (int i = 0; i < 4; ++i)
                gload_lds16(bwsrc + (size_t)(s + 2) * 16384 + i * 1024,
                            bpriv + (s & 1) * 4096 + i * 1024 + lane * 16);
            asm volatile("s_waitcnt vmcnt(4)" ::: "memory");
        } else if (s == 16) {
            asm volatile("s_waitcnt vmcnt(0)" ::: "memory");
        }
#pragma unroll
        for (int fn = 0; fn < 4; ++fn)
#pragma unroll
            for (int fm = 0; fm < 8; ++fm)
                acc[fn][fm] = __builtin_amdgcn_mfma_i32_16x16x64_i8(
                    bfr[fn], afr[fm], acc[fn][fm], 0, 0, 0);
    }

    // ---- epilogue: repack via LDS, float4 stores ----
    const float Mv  = *Mp;
    const float yzv = *yzp;
    const float CWf = 128.0f - *wzp;               // (128 - w_zero)
#pragma unroll
    for (int row = 0; row < 2; ++row) {
        __syncthreads();                           // LDS free (K-loop/pass done)
#pragma unroll
        for (int fn = 0; fn < 4; ++fn) {
#pragma unroll
            for (int reg = 0; reg < 4; ++reg) {
                const int cout = wn * 64 + fn * 16 + lg * 4 + reg;
                const float bv = bias[cout];
#pragma unroll
                for (int fm4 = 0; fm4 < 4; ++fm4) {
                    const int m = fm4 * 16 + l15;
                    float af = (float)acc[fn][row * 4 + fm4][reg] +
                               CWf * (float)s2row[row][m];
                    float v = fmaxf((af + bv) * Mv + yzv, yzv);
                    fbuf[cout * 66 + m] = rintf(v);
                }
            }
        }
        __syncthreads();                           // buffer complete
        const size_t obase = (size_t)b * 802816 + (size_t)(h0 + row) * 56;
#pragma unroll
        for (int k = 0; k < 16; ++k) {
            int c = tid + k * 256;                 // lane-contiguous chunks
            int cout = c >> 4, m4 = c & 15;
            if (m4 < 14) {                         // m4*4+3 <= 55
                f32x4 vv = *(const f32x4*)&fbuf[cout * 66 + m4 * 4];
                *(f32x4*)&out[obase + (size_t)cout * 3136 + m4 * 4] = vv;
            }
        }
    }
}

extern "C" void kernel_launch(void* const* d_in, const int* in_sizes, int n_in,
                              void* d_out, int out_size, void* d_ws, size_t ws_size,
                              hipStream_t stream) {
    const float* x    = (const float*)d_in[0];
    const float* w    = (const float*)d_in[1];
    const float* bias = (const float*)d_in[2];
    const float* Mp   = (const float*)d_in[3];
    const float* xzp  = (const float*)d_in[4];
    const float* wzp  = (const float*)d_in[5];
    const float* yzp  = (const float*)d_in[6];
    float* out = (float*)d_out;

    char* wt     = (char*)d_ws;                          // 288 KB
    char* xpi8   = wt + WTI8_BYTES;                      // 15.2 MB
    int*  colsum = (int*)(xpi8 + XPI8_BYTES);            // 475 KB

    prep_kernel<<<32 * 58 + 72, 256, 0, stream>>>(x, xzp, w, xpi8, colsum, wt);
    conv_kernel<<<32 * 28, 256, 0, stream>>>(wt, xpi8, colsum, bias, Mp, wzp, yzp, out);
}

// Round 27
// 70.619 us; speedup vs baseline: 9.2502x; 1.0649x over previous
//
#include <hip/hip_runtime.h>
#include <hip/hip_bf16.h>

// Quantized 3x3 conv via int8 implicit GEMM — consolidation round:
// R20 kernel (best-measured family: wave-private 2-slot B ring, counted
// per-wave vmcnt, zero in-loop barriers, DIRECT transposed-D epilogue)
// + fused single prep launch + T1 XCD-bijective block swizzle (896%8==0).
// B=32, Cin=128, Cout=256, H=W=56, pad=1. M=(b,h,w64), N=256, K=9x128.
//
// (x-xz)(w-wz) = xi*wi + (128-wz)*xi,  xi=x-128 (int8), wi=w-128 (int8);
// acc = i8gemm + (128-wz)*S,  S = window-sum of xi (pads contribute 0).
//
// xpi8 blob per (b,hh), 8KB: byte(w,c) = w*128 + (c ^ ((w&7)<<4)).
// wt layout: per (s=r*2+ch, wn) a 4KB panel of 64 rows x 64B:
//   byte(nn, kl) = nn*64 + (kl ^ ((nn&3)<<4)),  n = wn*64+nn, cin = ch*64+kl.
// Involution swizzles; staged linearly via global_load_lds, read with the
// same XOR (rule #21).

typedef __attribute__((ext_vector_type(4))) int   i32x4;
typedef __attribute__((ext_vector_type(4))) float f32x4;

#define WTI8_BYTES (18 * 16384)            // 294,912
#define XPI8_BYTES (32 * 58 * 8192)        // 15,204,352

__device__ __forceinline__ void gload_lds16(const void* g, void* l) {
    __builtin_amdgcn_global_load_lds(
        (const __attribute__((address_space(1))) void*)g,
        (__attribute__((address_space(3))) void*)l, 16, 0, 0);
}

// ---- fused prep: blocks <1856 do x-repack+colsum; rest do weight prep ----
__global__ void prep_kernel(const float* __restrict__ x, const float* __restrict__ xzp,
                            const float* __restrict__ w,
                            char* __restrict__ xpi8, int* __restrict__ colsum,
                            char* __restrict__ wt) {
    int tid = threadIdx.x;
    if (blockIdx.x >= 32 * 58) {
        int cidx = (blockIdx.x - 32 * 58) * 256 + tid;   // < 18432
        int byte0 = cidx * 16;
        int s    = byte0 >> 14;
        int wn   = (byte0 >> 12) & 3;
        int e4   = byte0 & 4095;
        int nn   = e4 >> 6;
        int koff = e4 & 63;
        int kl   = koff ^ ((nn & 3) << 4);
        int n = wn * 64 + nn;
        int r = s >> 1, ch = s & 1;
        union { char c[16]; i32x4 v; } u;
#pragma unroll
        for (int j = 0; j < 16; ++j) {
            int cin = ch * 64 + kl + j;
            u.c[j] = (char)((int)w[(size_t)n * 1152 + cin * 9 + r] - 128);
        }
        *(i32x4*)(wt + byte0) = u.v;
        return;
    }
    int bhh = blockIdx.x;
    int b = bhh / 58, hh = bhh % 58;
    char* blob = xpi8 + (size_t)bhh * 8192;
    int wcol = tid & 63;
    int cq = tid >> 6;
    __shared__ int ps[4][64];
    if (hh == 0 || hh == 57) {
        i32x4 z = {0, 0, 0, 0};
        *(i32x4*)(blob + tid * 32)      = z;
        *(i32x4*)(blob + tid * 32 + 16) = z;
        if (cq == 0) colsum[bhh * 64 + wcol] = 0;
        return;
    }
    const int ZX = (int)rintf(*xzp);
    bool valid = (wcol >= 1 && wcol <= 56);
    const float* xb = x + (size_t)b * 128 * 3136 + (size_t)(hh - 1) * 56 +
                      (valid ? (wcol - 1) : 0);
    int csum = 0;
#pragma unroll
    for (int u = 0; u < 2; ++u) {
        union { char c[16]; i32x4 v; } uu;
#pragma unroll
        for (int j = 0; j < 16; ++j) {
            int c = cq * 32 + u * 16 + j;
            int val = valid ? ((int)xb[(size_t)c * 3136] - ZX) : 0;
            uu.c[j] = (char)val;
            csum += val;
        }
        *(i32x4*)(blob + wcol * 128 + ((cq * 32 + u * 16) ^ ((wcol & 7) << 4))) = uu.v;
    }
    ps[cq][wcol] = csum;
    __syncthreads();
    if (cq == 0)
        colsum[bhh * 64 + wcol] = ps[0][wcol] + ps[1][wcol] + ps[2][wcol] + ps[3][wcol];
}

// ---- main conv: R20 structure + XCD swizzle ----
__global__ __launch_bounds__(256, 2)
void conv_kernel(const char* __restrict__ wt,
                 const char* __restrict__ xpi8,
                 const int* __restrict__ colsum,
                 const float* __restrict__ bias,
                 const float* __restrict__ Mp,
                 const float* __restrict__ wzp,
                 const float* __restrict__ yzp,
                 float* __restrict__ out) {
    __shared__ __align__(1024) char As[32768];     // A: 4 row-blobs, shared
    __shared__ __align__(1024) char Bp[32768];     // 4 waves x 2 slots x 4KB
    __shared__ int s2row[2][64];

    const int tid = threadIdx.x;
    const int lane = tid & 63;
    const int wn = tid >> 6;                       // 0..3: 64-cout slice
    const int l15 = lane & 15, lg = lane >> 4;
    // T1: XCD-bijective swizzle (nwg=896, 896%8==0 -> simple form bijective)
    const int bx = (blockIdx.x % 8) * 112 + (blockIdx.x / 8);
    const int b = bx / 28;
    const int h0 = (bx % 28) * 2;                  // 2 output rows per block

    char* bpriv = Bp + wn * 8192;                  // this wave's 2-slot ring
    const char* bwsrc = wt + wn * 4096 + lane * 16;
    const int bfoff = (lg * 16) ^ ((l15 & 3) << 4);

    // ---- prologue: A (32KB); B stages 0,1 -> slots 0,1; S2 rows ----
    const char* agbase = xpi8 + (size_t)(b * 58 + h0) * 8192;
#pragma unroll
    for (int i = 0; i < 8; ++i)
        gload_lds16(agbase + i * 4096 + tid * 16, As + i * 4096 + tid * 16);
#pragma unroll
    for (int st = 0; st < 2; ++st)
#pragma unroll
        for (int i = 0; i < 4; ++i)
            gload_lds16(bwsrc + (size_t)st * 16384 + i * 1024,
                        bpriv + st * 4096 + i * 1024 + lane * 16);
    if (tid < 128) {
        int row = tid >> 6, m = tid & 63;
        int s = 0;
        if (m < 56) {
#pragma unroll
            for (int kh = 0; kh < 3; ++kh)
#pragma unroll
                for (int kw = 0; kw < 3; ++kw)
                    s += colsum[(b * 58 + h0 + row + kh) * 64 + m + kw];
        }
        s2row[row][m] = s;
    }

    i32x4 acc[4][8];                               // [fn][fm]: row=cout, col=m
#pragma unroll
    for (int i = 0; i < 4; ++i)
#pragma unroll
        for (int j = 0; j < 8; ++j)
            acc[i][j] = (i32x4){0, 0, 0, 0};

    __syncthreads();                               // the ONLY barrier

#pragma unroll
    for (int s = 0; s < 18; ++s) {                 // 9 taps x 2 cin-halves
        const int kh = (s >> 1) / 3, kw = (s >> 1) % 3, ch = s & 1;
        const char* bslot = bpriv + (s & 1) * 4096;
        i32x4 bfr[4];
#pragma unroll
        for (int fn = 0; fn < 4; ++fn)
            bfr[fn] = *(const i32x4*)(bslot + (fn * 16 + l15) * 64 + bfoff);
        i32x4 afr[8];
#pragma unroll
        for (int fm = 0; fm < 8; ++fm) {
            int rowoff = fm >> 2;                  // 0..1: output row
            int wv = (fm & 3) * 16 + l15 + kw;
            int wc = wv > 63 ? 63 : wv;            // clamped lanes: dead outputs
            int ab = (rowoff + kh) * 8192 + wc * 128 +
                     ((ch * 64 + lg * 16) ^ ((wc & 7) << 4));
            afr[fm] = *(const i32x4*)(As + ab);
        }
        if (s < 16) {
            asm volatile("s_waitcnt lgkmcnt(0)" ::: "memory");
#pragma unroll
            for (int i = 0; i < 4; ++i)
                gload_lds16(bwsrc + (size_t)(s + 2) * 16384 + i * 1024,
                            bpriv + (s & 1) * 4096 + i * 1024 + lane * 16);
            asm volatile("s_waitcnt vmcnt(4)" ::: "memory");
        } else if (s == 16) {
            asm volatile("s_waitcnt vmcnt(0)" ::: "memory");
        }
#pragma unroll
        for (int fn = 0; fn < 4; ++fn)
#pragma unroll
            for (int fm = 0; fm < 8; ++fm)
                acc[fn][fm] = __builtin_amdgcn_mfma_i32_16x16x64_i8(
                    bfr[fn], afr[fm], acc[fn][fm], 0, 0, 0);
    }

    // ---- epilogue: direct transposed-D stores (coalesced in m) ----
    const float Mv  = *Mp;
    const float yzv = *yzp;
    const float CWf = 128.0f - *wzp;               // (128 - w_zero)
#pragma unroll
    for (int fn = 0; fn < 4; ++fn) {
#pragma unroll
        for (int reg = 0; reg < 4; ++reg) {
            const int cout = wn * 64 + fn * 16 + lg * 4 + reg;
            const float bv = bias[cout];
#pragma unroll
            for (int fm = 0; fm < 8; ++fm) {
                const int row = fm >> 2;
                const int m = (fm & 3) * 16 + l15; // lane-contiguous
                if (m < 56) {
                    const size_t rowb =
                        ((size_t)(b * 256 + cout) * 56 + h0 + row) * 56;
                    float af = (float)acc[fn][fm][reg] +
                               CWf * (float)s2row[row][m];
                    float v = (af + bv) * Mv + yzv;
                    v = fmaxf(v, yzv);
                    out[rowb + m] = rintf(v);
                }
            }
        }
    }
}

extern "C" void kernel_launch(void* const* d_in, const int* in_sizes, int n_in,
                              void* d_out, int out_size, void* d_ws, size_t ws_size,
                              hipStream_t stream) {
    const float* x    = (const float*)d_in[0];
    const float* w    = (const float*)d_in[1];
    const float* bias = (const float*)d_in[2];
    const float* Mp   = (const float*)d_in[3];
    const float* xzp  = (const float*)d_in[4];
    const float* wzp  = (const float*)d_in[5];
    const float* yzp  = (const float*)d_in[6];
    float* out = (float*)d_out;

    char* wt     = (char*)d_ws;                          // 288 KB
    char* xpi8   = wt + WTI8_BYTES;                      // 15.2 MB
    int*  colsum = (int*)(xpi8 + XPI8_BYTES);            // 475 KB

    prep_kernel<<<32 * 58 + 72, 256, 0, stream>>>(x, xzp, w, xpi8, colsum, wt);
    conv_kernel<<<32 * 28, 256, 0, stream>>>(wt, xpi8, colsum, bias, Mp, wzp, yzp, out);
}

// Round 28
// 69.315 us; speedup vs baseline: 9.4241x; 1.0188x over previous
//
#include <hip/hip_runtime.h>
#include <hip/hip_bf16.h>

// Quantized 3x3 conv via int8 implicit GEMM — R27 (best: 70.6us total) +
// T5 s_setprio(1) around the MFMA burst. Phase diversity now exists
// (2 barrier-free blocks/CU, XCD swizzle, wave-private rings) so the CU
// scheduler has something to arbitrate (m191 mechanism).
// B=32, Cin=128, Cout=256, H=W=56, pad=1. M=(b,h,w64), N=256, K=9x128.
//
// (x-xz)(w-wz) = xi*wi + (128-wz)*xi,  xi=x-128 (int8), wi=w-128 (int8);
// acc = i8gemm + (128-wz)*S,  S = window-sum of xi (pads contribute 0).
//
// xpi8 blob per (b,hh), 8KB: byte(w,c) = w*128 + (c ^ ((w&7)<<4)).
// wt layout: per (s=r*2+ch, wn) a 4KB panel of 64 rows x 64B:
//   byte(nn, kl) = nn*64 + (kl ^ ((nn&3)<<4)),  n = wn*64+nn, cin = ch*64+kl.
// Involution swizzles; staged linearly via global_load_lds, read with the
// same XOR (rule #21).

typedef __attribute__((ext_vector_type(4))) int   i32x4;
typedef __attribute__((ext_vector_type(4))) float f32x4;

#define WTI8_BYTES (18 * 16384)            // 294,912
#define XPI8_BYTES (32 * 58 * 8192)        // 15,204,352

__device__ __forceinline__ void gload_lds16(const void* g, void* l) {
    __builtin_amdgcn_global_load_lds(
        (const __attribute__((address_space(1))) void*)g,
        (__attribute__((address_space(3))) void*)l, 16, 0, 0);
}

// ---- fused prep: blocks <1856 do x-repack+colsum; rest do weight prep ----
__global__ void prep_kernel(const float* __restrict__ x, const float* __restrict__ xzp,
                            const float* __restrict__ w,
                            char* __restrict__ xpi8, int* __restrict__ colsum,
                            char* __restrict__ wt) {
    int tid = threadIdx.x;
    if (blockIdx.x >= 32 * 58) {
        int cidx = (blockIdx.x - 32 * 58) * 256 + tid;   // < 18432
        int byte0 = cidx * 16;
        int s    = byte0 >> 14;
        int wn   = (byte0 >> 12) & 3;
        int e4   = byte0 & 4095;
        int nn   = e4 >> 6;
        int koff = e4 & 63;
        int kl   = koff ^ ((nn & 3) << 4);
        int n = wn * 64 + nn;
        int r = s >> 1, ch = s & 1;
        union { char c[16]; i32x4 v; } u;
#pragma unroll
        for (int j = 0; j < 16; ++j) {
            int cin = ch * 64 + kl + j;
            u.c[j] = (char)((int)w[(size_t)n * 1152 + cin * 9 + r] - 128);
        }
        *(i32x4*)(wt + byte0) = u.v;
        return;
    }
    int bhh = blockIdx.x;
    int b = bhh / 58, hh = bhh % 58;
    char* blob = xpi8 + (size_t)bhh * 8192;
    int wcol = tid & 63;
    int cq = tid >> 6;
    __shared__ int ps[4][64];
    if (hh == 0 || hh == 57) {
        i32x4 z = {0, 0, 0, 0};
        *(i32x4*)(blob + tid * 32)      = z;
        *(i32x4*)(blob + tid * 32 + 16) = z;
        if (cq == 0) colsum[bhh * 64 + wcol] = 0;
        return;
    }
    const int ZX = (int)rintf(*xzp);
    bool valid = (wcol >= 1 && wcol <= 56);
    const float* xb = x + (size_t)b * 128 * 3136 + (size_t)(hh - 1) * 56 +
                      (valid ? (wcol - 1) : 0);
    int csum = 0;
#pragma unroll
    for (int u = 0; u < 2; ++u) {
        union { char c[16]; i32x4 v; } uu;
#pragma unroll
        for (int j = 0; j < 16; ++j) {
            int c = cq * 32 + u * 16 + j;
            int val = valid ? ((int)xb[(size_t)c * 3136] - ZX) : 0;
            uu.c[j] = (char)val;
            csum += val;
        }
        *(i32x4*)(blob + wcol * 128 + ((cq * 32 + u * 16) ^ ((wcol & 7) << 4))) = uu.v;
    }
    ps[cq][wcol] = csum;
    __syncthreads();
    if (cq == 0)
        colsum[bhh * 64 + wcol] = ps[0][wcol] + ps[1][wcol] + ps[2][wcol] + ps[3][wcol];
}

// ---- main conv: R27 structure + setprio around MFMA ----
__global__ __launch_bounds__(256, 2)
void conv_kernel(const char* __restrict__ wt,
                 const char* __restrict__ xpi8,
                 const int* __restrict__ colsum,
                 const float* __restrict__ bias,
                 const float* __restrict__ Mp,
                 const float* __restrict__ wzp,
                 const float* __restrict__ yzp,
                 float* __restrict__ out) {
    __shared__ __align__(1024) char As[32768];     // A: 4 row-blobs, shared
    __shared__ __align__(1024) char Bp[32768];     // 4 waves x 2 slots x 4KB
    __shared__ int s2row[2][64];

    const int tid = threadIdx.x;
    const int lane = tid & 63;
    const int wn = tid >> 6;                       // 0..3: 64-cout slice
    const int l15 = lane & 15, lg = lane >> 4;
    // T1: XCD-bijective swizzle (nwg=896, 896%8==0 -> simple form bijective)
    const int bx = (blockIdx.x % 8) * 112 + (blockIdx.x / 8);
    const int b = bx / 28;
    const int h0 = (bx % 28) * 2;                  // 2 output rows per block

    char* bpriv = Bp + wn * 8192;                  // this wave's 2-slot ring
    const char* bwsrc = wt + wn * 4096 + lane * 16;
    const int bfoff = (lg * 16) ^ ((l15 & 3) << 4);

    // ---- prologue: A (32KB); B stages 0,1 -> slots 0,1; S2 rows ----
    const char* agbase = xpi8 + (size_t)(b * 58 + h0) * 8192;
#pragma unroll
    for (int i = 0; i < 8; ++i)
        gload_lds16(agbase + i * 4096 + tid * 16, As + i * 4096 + tid * 16);
#pragma unroll
    for (int st = 0; st < 2; ++st)
#pragma unroll
        for (int i = 0; i < 4; ++i)
            gload_lds16(bwsrc + (size_t)st * 16384 + i * 1024,
                        bpriv + st * 4096 + i * 1024 + lane * 16);
    if (tid < 128) {
        int row = tid >> 6, m = tid & 63;
        int s = 0;
        if (m < 56) {
#pragma unroll
            for (int kh = 0; kh < 3; ++kh)
#pragma unroll
                for (int kw = 0; kw < 3; ++kw)
                    s += colsum[(b * 58 + h0 + row + kh) * 64 + m + kw];
        }
        s2row[row][m] = s;
    }

    i32x4 acc[4][8];                               // [fn][fm]: row=cout, col=m
#pragma unroll
    for (int i = 0; i < 4; ++i)
#pragma unroll
        for (int j = 0; j < 8; ++j)
            acc[i][j] = (i32x4){0, 0, 0, 0};

    __syncthreads();                               // the ONLY barrier

#pragma unroll
    for (int s = 0; s < 18; ++s) {                 // 9 taps x 2 cin-halves
        const int kh = (s >> 1) / 3, kw = (s >> 1) % 3, ch = s & 1;
        const char* bslot = bpriv + (s & 1) * 4096;
        i32x4 bfr[4];
#pragma unroll
        for (int fn = 0; fn < 4; ++fn)
            bfr[fn] = *(const i32x4*)(bslot + (fn * 16 + l15) * 64 + bfoff);
        i32x4 afr[8];
#pragma unroll
        for (int fm = 0; fm < 8; ++fm) {
            int rowoff = fm >> 2;                  // 0..1: output row
            int wv = (fm & 3) * 16 + l15 + kw;
            int wc = wv > 63 ? 63 : wv;            // clamped lanes: dead outputs
            int ab = (rowoff + kh) * 8192 + wc * 128 +
                     ((ch * 64 + lg * 16) ^ ((wc & 7) << 4));
            afr[fm] = *(const i32x4*)(As + ab);
        }
        if (s < 16) {
            asm volatile("s_waitcnt lgkmcnt(0)" ::: "memory");
#pragma unroll
            for (int i = 0; i < 4; ++i)
                gload_lds16(bwsrc + (size_t)(s + 2) * 16384 + i * 1024,
                            bpriv + (s & 1) * 4096 + i * 1024 + lane * 16);
            asm volatile("s_waitcnt vmcnt(4)" ::: "memory");
        } else if (s == 16) {
            asm volatile("s_waitcnt vmcnt(0)" ::: "memory");
        }
        __builtin_amdgcn_s_setprio(1);             // T5: favor MFMA-entering wave
#pragma unroll
        for (int fn = 0; fn < 4; ++fn)
#pragma unroll
            for (int fm = 0; fm < 8; ++fm)
                acc[fn][fm] = __builtin_amdgcn_mfma_i32_16x16x64_i8(
                    bfr[fn], afr[fm], acc[fn][fm], 0, 0, 0);
        __builtin_amdgcn_s_setprio(0);
    }

    // ---- epilogue: direct transposed-D stores (coalesced in m) ----
    const float Mv  = *Mp;
    const float yzv = *yzp;
    const float CWf = 128.0f - *wzp;               // (128 - w_zero)
#pragma unroll
    for (int fn = 0; fn < 4; ++fn) {
#pragma unroll
        for (int reg = 0; reg < 4; ++reg) {
            const int cout = wn * 64 + fn * 16 + lg * 4 + reg;
            const float bv = bias[cout];
#pragma unroll
            for (int fm = 0; fm < 8; ++fm) {
                const int row = fm >> 2;
                const int m = (fm & 3) * 16 + l15; // lane-contiguous
                if (m < 56) {
                    const size_t rowb =
                        ((size_t)(b * 256 + cout) * 56 + h0 + row) * 56;
                    float af = (float)acc[fn][fm][reg] +
                               CWf * (float)s2row[row][m];
                    float v = (af + bv) * Mv + yzv;
                    v = fmaxf(v, yzv);
                    out[rowb + m] = rintf(v);
                }
            }
        }
    }
}

extern "C" void kernel_launch(void* const* d_in, const int* in_sizes, int n_in,
                              void* d_out, int out_size, void* d_ws, size_t ws_size,
                              hipStream_t stream) {
    const float* x    = (const float*)d_in[0];
    const float* w    = (const float*)d_in[1];
    const float* bias = (const float*)d_in[2];
    const float* Mp   = (const float*)d_in[3];
    const float* xzp  = (const float*)d_in[4];
    const float* wzp  = (const float*)d_in[5];
    const float* yzp  = (const float*)d_in[6];
    float* out = (float*)d_out;

    char* wt     = (char*)d_ws;                          // 288 KB
    char* xpi8   = wt + WTI8_BYTES;                      // 15.2 MB
    int*  colsum = (int*)(xpi8 + XPI8_BYTES);            // 475 KB

    prep_kernel<<<32 * 58 + 72, 256, 0, stream>>>(x, xzp, w, xpi8, colsum, wt);
    conv_kernel<<<32 * 28, 256, 0, stream>>>(wt, xpi8, colsum, bias, Mp, wzp, yzp, out);
}